// Round 20
// baseline (126.210 us; speedup 1.0000x reference)
//
#include <hip/hip_runtime.h>

#define H 12
#define S 2048
#define D 768
#define HD 64
#define BATCH 4
#define M_TOT (BATCH * S)   // 8192

typedef __attribute__((ext_vector_type(8))) short bf16x8;
typedef __attribute__((ext_vector_type(4))) float f32x4;

__device__ __forceinline__ ushort f2bf(float f) {
  unsigned int x = __float_as_uint(f);
  x += 0x7fffu + ((x >> 16) & 1u);
  return (ushort)(x >> 16);
}

__device__ __forceinline__ uint cvt_pk_bf16(float lo, float hi) {
  uint r;
  asm("v_cvt_pk_bf16_f32 %0, %1, %2" : "=v"(r) : "v"(lo), "v"(hi));
  return r;
}

__device__ __forceinline__ void gload_lds16(const void* gsrc, void* lds) {
  __builtin_amdgcn_global_load_lds(
      (const __attribute__((address_space(1))) unsigned int*)gsrc,
      (__attribute__((address_space(3))) unsigned int*)lds, 16, 0, 0);
}

// ---------------- fused cast fp32 -> bf16 (x + 4 weights) ----------------
__global__ __launch_bounds__(256) void cast_all(
    const float* __restrict__ x, const float* __restrict__ wq,
    const float* __restrict__ wk, const float* __restrict__ wv,
    const float* __restrict__ wo, ushort* __restrict__ xb,
    ushort* __restrict__ wqb, ushort* __restrict__ wkb,
    ushort* __restrict__ wvb, ushort* __restrict__ wob) {
  const int NX = M_TOT * D / 4;
  const int NW = D * D / 4;
  int i = blockIdx.x * 256 + threadIdx.x;
  const float* src; ushort* dst; int off;
  if (i < NX) { src = x; dst = xb; off = i; }
  else {
    int j = i - NX; int w = j / NW; off = j - w * NW;
    src = (w == 0) ? wq : (w == 1) ? wk : (w == 2) ? wv : wo;
    dst = (w == 0) ? wqb : (w == 1) ? wkb : (w == 2) ? wvb : wob;
  }
  float4 f = reinterpret_cast<const float4*>(src)[off];
  ushort4 u;
  u.x = f2bf(f.x); u.y = f2bf(f.y); u.z = f2bf(f.z); u.w = f2bf(f.w);
  reinterpret_cast<ushort4*>(dst)[off] = u;
}

// ---------------- FUSED Q+K+V GEMM (round-15 proven): one x-stage -> 3 outputs ----------------
__global__ __launch_bounds__(256, 3) void gemm_qkv(
    const ushort* __restrict__ xb, const ushort* __restrict__ wqb,
    const ushort* __restrict__ wkb, const ushort* __restrict__ wvb,
    ushort* __restrict__ qb, ushort* __restrict__ kb_,
    ushort* __restrict__ vtb, float qscale) {
  __shared__ ushort SM[2][10240];  // 40 KB
  const int tid = threadIdx.x;
  const int lane = tid & 63, wid = tid >> 6;
  const int g = lane >> 4, li = lane & 15;

  const int wg = blockIdx.x;
  const int mt = wg & 63, slab = wg >> 6;
  const int m0 = mt * 128, n0 = slab * 64;

  const ushort* xm = xb + (size_t)m0 * 768;
  const ushort* wqn = wqb + (size_t)n0 * 768;
  const ushort* wkn = wkb + (size_t)n0 * 768;
  const ushort* wvn = wvb + (size_t)n0 * 768;

  const int rsub = lane >> 2;
  const int coff = (((lane & 3) ^ ((rsub >> 1) & 3)) << 3);
  const int wrow = wid * 16;

  auto stage = [&](int buf, int k0) {
#pragma unroll
    for (int rnd = 0; rnd < 2; ++rnd) {
      const int row0 = rnd * 64 + wrow;
      gload_lds16(&xm[(size_t)(row0 + rsub) * 768 + k0 + coff], &SM[buf][row0 * 32]);
    }
    gload_lds16(&wqn[(size_t)(wrow + rsub) * 768 + k0 + coff], &SM[buf][4096 + wrow * 32]);
    gload_lds16(&wkn[(size_t)(wrow + rsub) * 768 + k0 + coff], &SM[buf][6144 + wrow * 32]);
    gload_lds16(&wvn[(size_t)(wrow + rsub) * 768 + k0 + coff], &SM[buf][8192 + wrow * 32]);
  };

  f32x4 acc[3][2][4] = {};
  stage(0, 0);

  for (int kt = 0; kt < 24; ++kt) {
    const int cur = kt & 1;
    asm volatile("s_waitcnt vmcnt(0)" ::: "memory");
    __syncthreads();
    if (kt + 1 < 24) stage(cur ^ 1, (kt + 1) * 32);

    const ushort* bp = &SM[cur][0];
    bf16x8 a[2];
#pragma unroll
    for (int i = 0; i < 2; ++i) {
      const int row = wid * 32 + i * 16 + li;
      a[i] = *reinterpret_cast<const bf16x8*>(
          &bp[row * 32 + ((g ^ ((row >> 1) & 3)) << 3)]);
    }
#pragma unroll
    for (int o = 0; o < 3; ++o) {
      const int off = 4096 + o * 2048;
      bf16x8 b[4];
#pragma unroll
      for (int j = 0; j < 4; ++j) {
        const int row = j * 16 + li;
        b[j] = *reinterpret_cast<const bf16x8*>(
            &bp[off + row * 32 + ((g ^ ((row >> 1) & 3)) << 3)]);
      }
      __builtin_amdgcn_s_setprio(1);
#pragma unroll
      for (int i = 0; i < 2; ++i)
#pragma unroll
        for (int j = 0; j < 4; ++j)
          acc[o][i][j] = __builtin_amdgcn_mfma_f32_16x16x32_bf16(a[i], b[j], acc[o][i][j], 0, 0, 0);
      __builtin_amdgcn_s_setprio(0);
    }
  }

  ushort* Cs = &SM[0][0];
  const int b0 = m0 >> 11, sb = m0 & 2047;

  // ---- Q + K epilogue (two 128x64 tiles, swizzled LDS round-trip) ----
  __syncthreads();
#pragma unroll
  for (int o = 0; o < 2; ++o)
#pragma unroll
    for (int i = 0; i < 2; ++i)
#pragma unroll
      for (int j = 0; j < 4; ++j)
#pragma unroll
        for (int rr = 0; rr < 4; ++rr) {
          const int row = wid * 32 + i * 16 + g * 4 + rr;
          const int col = j * 16 + li;
          const int pc = ((((col >> 3) ^ (row & 7)) << 3) | (col & 7));
          const float v = acc[o][i][j][rr] * (o == 0 ? qscale : 1.0f);
          Cs[o * 8192 + row * 64 + pc] = f2bf(v);
        }
  __syncthreads();
  {
    const int row = tid >> 1, half = tid & 1;
    const int m = m0 + row;
    const size_t rb = (((size_t)b0 * H + slab) * S + (m & 2047)) * HD + half * 32;
    ushort* dq = &qb[rb];
    ushort* dk = &kb_[rb];
#pragma unroll
    for (int c8 = 0; c8 < 4; ++c8) {
      const int col = half * 32 + c8 * 8;
      const int chunk = (col >> 3) ^ (row & 7);
      *reinterpret_cast<bf16x8*>(&dq[c8 * 8]) =
          *reinterpret_cast<const bf16x8*>(&Cs[row * 64 + chunk * 8]);
      *reinterpret_cast<bf16x8*>(&dk[c8 * 8]) =
          *reinterpret_cast<const bf16x8*>(&Cs[8192 + row * 64 + chunk * 8]);
    }
  }

  // ---- V epilogue: write transposed Cs_v[64 feat][128 tok] ----
  __syncthreads();
#pragma unroll
  for (int i = 0; i < 2; ++i)
#pragma unroll
    for (int j = 0; j < 4; ++j)
#pragma unroll
      for (int rr = 0; rr < 4; ++rr) {
        const int tok = wid * 32 + i * 16 + g * 4 + rr;
        const int feat = j * 16 + li;
        const int pc = ((((tok >> 3) ^ (feat & 7)) << 3) | (tok & 7));
        Cs[feat * 128 + pc] = f2bf(acc[2][i][j][rr]);
      }
  __syncthreads();
  {
    const int feat = tid >> 2, qtr = tid & 3;
    ushort* dv = &vtb[(((size_t)b0 * H + slab) * HD + feat) * S + sb + qtr * 32];
#pragma unroll
    for (int c8 = 0; c8 < 4; ++c8) {
      const int tok = qtr * 32 + c8 * 8;
      const int chunk = (tok >> 3) ^ (feat & 7);
      *reinterpret_cast<bf16x8*>(&dv[c8 * 8]) =
          *reinterpret_cast<const bf16x8*>(&Cs[feat * 128 + chunk * 8]);
    }
  }
}

// ---------------- WO GEMM (round-10 best): 64x128 tiles, (128,6), 3-deep ----------------
__global__ __launch_bounds__(256) void gemm_wo(const ushort* __restrict__ A,
                                               const ushort* __restrict__ W,
                                               float* __restrict__ out_f,
                                               const float* __restrict__ bias) {
  __shared__ ushort SM[3][6144];
  const int tid = threadIdx.x;
  const int lane = tid & 63, wid = tid >> 6;
  const int g = lane >> 4, li = lane & 15;
  const int wm = wid >> 1, wn = wid & 1;
  const int m0 = blockIdx.x * 64, n0 = blockIdx.y * 128;

  const int rsub = lane >> 2;
  const int coff = (((lane & 3) ^ ((rsub >> 1) & 3)) << 3);

  auto stage = [&](int buf, int k0) {
    gload_lds16(&A[(size_t)(m0 + wid * 16 + rsub) * 768 + k0 + coff],
                &SM[buf][wid * 16 * 32]);
#pragma unroll
    for (int rnd = 0; rnd < 2; ++rnd) {
      const int row0 = rnd * 64 + wid * 16;
      gload_lds16(&W[(size_t)(n0 + row0 + rsub) * 768 + k0 + coff],
                  &SM[buf][2048 + row0 * 32]);
    }
  };

  f32x4 acc[2][4] = {};
  stage(0, 0);
  stage(1, 32);

  int cur = 0, pre = 2;
  for (int kt = 0; kt < 24; ++kt) {
    if (kt < 23) asm volatile("s_waitcnt vmcnt(3) lgkmcnt(0)" ::: "memory");
    else         asm volatile("s_waitcnt vmcnt(0) lgkmcnt(0)" ::: "memory");
    __builtin_amdgcn_s_barrier();
    if (kt + 2 < 24) stage(pre, (kt + 2) * 32);

    bf16x8 a[2], b[4];
#pragma unroll
    for (int i = 0; i < 2; ++i) {
      const int row = wm * 32 + i * 16 + li;
      a[i] = *reinterpret_cast<const bf16x8*>(
          &SM[cur][row * 32 + ((g ^ ((row >> 1) & 3)) << 3)]);
    }
#pragma unroll
    for (int j = 0; j < 4; ++j) {
      const int row = wn * 64 + j * 16 + li;
      b[j] = *reinterpret_cast<const bf16x8*>(
          &SM[cur][2048 + row * 32 + ((g ^ ((row >> 1) & 3)) << 3)]);
    }
    __builtin_amdgcn_s_setprio(1);
#pragma unroll
    for (int i = 0; i < 2; ++i)
#pragma unroll
      for (int j = 0; j < 4; ++j)
        acc[i][j] = __builtin_amdgcn_mfma_f32_16x16x32_bf16(a[i], b[j], acc[i][j], 0, 0, 0);
    __builtin_amdgcn_s_setprio(0);

    cur = (cur == 2) ? 0 : cur + 1;
    pre = (pre == 2) ? 0 : pre + 1;
  }

#pragma unroll
  for (int i = 0; i < 2; ++i)
#pragma unroll
    for (int j = 0; j < 4; ++j)
#pragma unroll
      for (int r = 0; r < 4; ++r) {
        const int m = m0 + wm * 32 + i * 16 + g * 4 + r;
        const int n = n0 + wn * 64 + j * 16 + li;
        out_f[(size_t)m * 768 + n] = acc[i][j][r] + bias[n];
      }
}

// ---------------- flash attention (round-18 proven): dual-fragment waves + l-via-MFMA ----------------
__global__ __launch_bounds__(256) void attn_kernel(const ushort* __restrict__ Q,
                                                   const ushort* __restrict__ K,
                                                   const ushort* __restrict__ VT,
                                                   ushort* __restrict__ ctx) {
  __shared__ ushort Ks[2][64 * 64];
  __shared__ ushort Vts[2][64 * 64];
  __shared__ ushort Ps[4][32][72];   // 51.2 KB total

  const int tid = threadIdx.x;
  const int lane = tid & 63, wid = tid >> 6;
  const int g = lane >> 4, li = lane & 15;

  const int wg = blockIdx.x;
  const int xcd = wg & 7, t = wg >> 3;
  const int bh = xcd + 8 * (t >> 4);
  const int p = t & 15;
  const int qL = 64 * (31 - p), qS = 64 * p;

  const size_t base = (size_t)bh * S * HD;
  const size_t vtbase = (size_t)bh * HD * S;

  bf16x8 aq[2][2];
#pragma unroll
  for (int f = 0; f < 2; ++f) {
    const size_t qr = base + (size_t)((f ? qS : qL) + wid * 16 + li) * HD;
#pragma unroll
    for (int c = 0; c < 2; ++c)
      aq[f][c] = *reinterpret_cast<const bf16x8*>(&Q[qr + c * 32 + g * 8]);
  }

  f32x4 acc[2][4] = {};
  f32x4 accl[2] = {};
  const uint one2 = 0x3F803F80u;           // two bf16 1.0
  uint4 ouv = {one2, one2, one2, one2};
  const bf16x8 ones8 = *reinterpret_cast<const bf16x8*>(&ouv);

  const int nkt = 32 - p;

  const int rsub = lane >> 3;
  const int c8e = (((lane & 7) ^ rsub) << 3);

  auto stage = [&](int buf, int k0) {
#pragma unroll
    for (int rnd = 0; rnd < 2; ++rnd) {
      const int row0 = rnd * 32 + wid * 8;
      gload_lds16(&K[base + (size_t)(k0 + row0 + rsub) * HD + c8e], &Ks[buf][row0 << 6]);
      gload_lds16(&VT[vtbase + (size_t)(row0 + rsub) * S + k0 + c8e], &Vts[buf][row0 << 6]);
    }
  };

  stage(0, 0);

  for (int kt = 0; kt < nkt; ++kt) {
    const int cur = kt & 1;
    const int k0 = kt * 64;
    const bool doS = (kt <= p);

    asm volatile("s_waitcnt vmcnt(0)" ::: "memory");
    __syncthreads();
    if (kt + 1 < nkt) stage(cur ^ 1, k0 + 64);

    f32x4 sc[2][4];
    __builtin_amdgcn_s_setprio(1);
#pragma unroll
    for (int ct = 0; ct < 4; ++ct) {
      const int row = ct * 16 + li, r7 = row & 7;
      const ushort* kr = &Ks[cur][row << 6];
      bf16x8 kb0 = *reinterpret_cast<const bf16x8*>(&kr[(g ^ r7) << 3]);
      bf16x8 kb1 = *reinterpret_cast<const bf16x8*>(&kr[((4 + g) ^ r7) << 3]);
      {
        f32x4 z = {};
        z = __builtin_amdgcn_mfma_f32_16x16x32_bf16(kb0, aq[0][0], z, 0, 0, 0);
        z = __builtin_amdgcn_mfma_f32_16x16x32_bf16(kb1, aq[0][1], z, 0, 0, 0);
        sc[0][ct] = z;
      }
      if (doS) {
        f32x4 z = {};
        z = __builtin_amdgcn_mfma_f32_16x16x32_bf16(kb0, aq[1][0], z, 0, 0, 0);
        z = __builtin_amdgcn_mfma_f32_16x16x32_bf16(kb1, aq[1][1], z, 0, 0, 0);
        sc[1][ct] = z;
      }
    }
    __builtin_amdgcn_s_setprio(0);

    if (kt == nkt - 1) {  // f=0 diagonal
      const int q = qL + wid * 16 + li;
#pragma unroll
      for (int ct = 0; ct < 4; ++ct)
#pragma unroll
        for (int r = 0; r < 4; ++r)
          if (k0 + ct * 16 + 4 * g + r > q) sc[0][ct][r] = -1e30f;
    }
    if (kt == p) {  // f=1 diagonal
      const int q = qS + wid * 16 + li;
#pragma unroll
      for (int ct = 0; ct < 4; ++ct)
#pragma unroll
        for (int r = 0; r < 4; ++r)
          if (k0 + ct * 16 + 4 * g + r > q) sc[1][ct][r] = -1e30f;
    }

    // ---- p = exp2(s), packed bf16 to wave-private LDS (no VALU l-adds) ----
#pragma unroll
    for (int f = 0; f < 2; ++f) {
      if (f == 1 && !doS) break;
#pragma unroll
      for (int ct = 0; ct < 4; ++ct) {
        float p0 = __builtin_amdgcn_exp2f(sc[f][ct][0]);
        float p1 = __builtin_amdgcn_exp2f(sc[f][ct][1]);
        float p2 = __builtin_amdgcn_exp2f(sc[f][ct][2]);
        float p3 = __builtin_amdgcn_exp2f(sc[f][ct][3]);
        uint2 pw;
        pw.x = cvt_pk_bf16(p0, p1);
        pw.y = cvt_pk_bf16(p2, p3);
        *reinterpret_cast<uint2*>(&Ps[wid][f * 16 + li][ct * 16 + 4 * g]) = pw;
      }
    }

    // ---- PV + l-via-MFMA ----
    bf16x8 pa[2][2];
    pa[0][0] = *reinterpret_cast<const bf16x8*>(&Ps[wid][li][g * 8]);
    pa[0][1] = *reinterpret_cast<const bf16x8*>(&Ps[wid][li][32 + g * 8]);
    if (doS) {
      pa[1][0] = *reinterpret_cast<const bf16x8*>(&Ps[wid][16 + li][g * 8]);
      pa[1][1] = *reinterpret_cast<const bf16x8*>(&Ps[wid][16 + li][32 + g * 8]);
    }
    __builtin_amdgcn_s_setprio(1);
    accl[0] = __builtin_amdgcn_mfma_f32_16x16x32_bf16(pa[0][0], ones8, accl[0], 0, 0, 0);
    accl[0] = __builtin_amdgcn_mfma_f32_16x16x32_bf16(pa[0][1], ones8, accl[0], 0, 0, 0);
    if (doS) {
      accl[1] = __builtin_amdgcn_mfma_f32_16x16x32_bf16(pa[1][0], ones8, accl[1], 0, 0, 0);
      accl[1] = __builtin_amdgcn_mfma_f32_16x16x32_bf16(pa[1][1], ones8, accl[1], 0, 0, 0);
    }
#pragma unroll
    for (int dt = 0; dt < 4; ++dt) {
      const int row = dt * 16 + li, r7 = row & 7;
      const ushort* vr = &Vts[cur][row << 6];
      bf16x8 vb0 = *reinterpret_cast<const bf16x8*>(&vr[(g ^ r7) << 3]);
      bf16x8 vb1 = *reinterpret_cast<const bf16x8*>(&vr[((4 + g) ^ r7) << 3]);
      acc[0][dt] = __builtin_amdgcn_mfma_f32_16x16x32_bf16(pa[0][0], vb0, acc[0][dt], 0, 0, 0);
      acc[0][dt] = __builtin_amdgcn_mfma_f32_16x16x32_bf16(pa[0][1], vb1, acc[0][dt], 0, 0, 0);
      if (doS) {
        acc[1][dt] = __builtin_amdgcn_mfma_f32_16x16x32_bf16(pa[1][0], vb0, acc[1][dt], 0, 0, 0);
        acc[1][dt] = __builtin_amdgcn_mfma_f32_16x16x32_bf16(pa[1][1], vb1, acc[1][dt], 0, 0, 0);
      }
    }
    __builtin_amdgcn_s_setprio(0);
  }

  // ---- normalize + store: accl[f][r] IS l for this lane's row, no shuffles ----
  const int b = bh / H, h = bh % H;
#pragma unroll
  for (int f = 0; f < 2; ++f) {
#pragma unroll
    for (int r = 0; r < 4; ++r) {
      const float inv = 1.0f / accl[f][r];
      const int s = (f ? qS : qL) + wid * 16 + 4 * g + r;
#pragma unroll
      for (int dt = 0; dt < 4; ++dt)
        ctx[((size_t)(b * S + s)) * D + h * HD + dt * 16 + li] =
            f2bf(acc[f][dt][r] * inv);
    }
  }
}

extern "C" void kernel_launch(void* const* d_in, const int* in_sizes, int n_in,
                              void* d_out, int out_size, void* d_ws, size_t ws_size,
                              hipStream_t stream) {
  (void)in_sizes; (void)n_in; (void)out_size; (void)ws_size;
  const float* x  = (const float*)d_in[0];
  const float* wq = (const float*)d_in[1];
  const float* wk = (const float*)d_in[2];
  const float* wv = (const float*)d_in[3];
  const float* wo = (const float*)d_in[4];
  const float* bo = (const float*)d_in[5];
  float* out = (float*)d_out;

  const size_t xn = (size_t)M_TOT * D;
  const size_t wn = (size_t)D * D;

  ushort* p = (ushort*)d_ws;
  ushort* x_bf  = p; p += xn;
  ushort* wq_bf = p; p += wn;
  ushort* wk_bf = p; p += wn;
  ushort* wv_bf = p; p += wn;
  ushort* wo_bf = p; p += wn;
  ushort* q_bf  = p; p += xn;
  ushort* k_bf  = p; p += xn;
  ushort* vt_bf = p; p += xn;
  ushort* ctx_bf = x_bf;  // alias: x_bf dead after QKV GEMM

  cast_all<<<8448, 256, 0, stream>>>(x, wq, wk, wv, wo,
                                     x_bf, wq_bf, wk_bf, wv_bf, wo_bf);

  const float QSCALE = 0.125f * 1.44269504f;  // 1/sqrt(64) * log2(e) folded into Q
  gemm_qkv<<<768, 256, 0, stream>>>(x_bf, wq_bf, wk_bf, wv_bf,
                                    q_bf, k_bf, vt_bf, QSCALE);

  attn_kernel<<<768, 256, 0, stream>>>(q_bf, k_bf, vt_bf, ctx_bf);

  gemm_wo<<<dim3(128, 6), 256, 0, stream>>>(ctx_bf, wo_bf, out, bo);
}

// Round 21
// 121.921 us; speedup vs baseline: 1.0352x; 1.0352x over previous
//
#include <hip/hip_runtime.h>

#define H 12
#define S 2048
#define D 768
#define HD 64
#define BATCH 4
#define M_TOT (BATCH * S)   // 8192

typedef __attribute__((ext_vector_type(8))) short bf16x8;
typedef __attribute__((ext_vector_type(4))) float f32x4;

__device__ __forceinline__ ushort f2bf(float f) {
  unsigned int x = __float_as_uint(f);
  x += 0x7fffu + ((x >> 16) & 1u);
  return (ushort)(x >> 16);
}

__device__ __forceinline__ uint cvt_pk_bf16(float lo, float hi) {
  uint r;
  asm("v_cvt_pk_bf16_f32 %0, %1, %2" : "=v"(r) : "v"(lo), "v"(hi));
  return r;
}

__device__ __forceinline__ void gload_lds16(const void* gsrc, void* lds) {
  __builtin_amdgcn_global_load_lds(
      (const __attribute__((address_space(1))) unsigned int*)gsrc,
      (__attribute__((address_space(3))) unsigned int*)lds, 16, 0, 0);
}

// ---------------- fused cast fp32 -> bf16 (x + 4 weights) ----------------
__global__ __launch_bounds__(256) void cast_all(
    const float* __restrict__ x, const float* __restrict__ wq,
    const float* __restrict__ wk, const float* __restrict__ wv,
    const float* __restrict__ wo, ushort* __restrict__ xb,
    ushort* __restrict__ wqb, ushort* __restrict__ wkb,
    ushort* __restrict__ wvb, ushort* __restrict__ wob) {
  const int NX = M_TOT * D / 4;
  const int NW = D * D / 4;
  int i = blockIdx.x * 256 + threadIdx.x;
  const float* src; ushort* dst; int off;
  if (i < NX) { src = x; dst = xb; off = i; }
  else {
    int j = i - NX; int w = j / NW; off = j - w * NW;
    src = (w == 0) ? wq : (w == 1) ? wk : (w == 2) ? wv : wo;
    dst = (w == 0) ? wqb : (w == 1) ? wkb : (w == 2) ? wvb : wob;
  }
  float4 f = reinterpret_cast<const float4*>(src)[off];
  ushort4 u;
  u.x = f2bf(f.x); u.y = f2bf(f.y); u.z = f2bf(f.z); u.w = f2bf(f.w);
  reinterpret_cast<ushort4*>(dst)[off] = u;
}

// ---------------- FUSED Q+K+V GEMM (round-15 proven): one x-stage -> 3 outputs ----------------
__global__ __launch_bounds__(256, 3) void gemm_qkv(
    const ushort* __restrict__ xb, const ushort* __restrict__ wqb,
    const ushort* __restrict__ wkb, const ushort* __restrict__ wvb,
    ushort* __restrict__ qb, ushort* __restrict__ kb_,
    ushort* __restrict__ vtb, float qscale) {
  __shared__ ushort SM[2][10240];  // 40 KB
  const int tid = threadIdx.x;
  const int lane = tid & 63, wid = tid >> 6;
  const int g = lane >> 4, li = lane & 15;

  const int wg = blockIdx.x;
  const int mt = wg & 63, slab = wg >> 6;
  const int m0 = mt * 128, n0 = slab * 64;

  const ushort* xm = xb + (size_t)m0 * 768;
  const ushort* wqn = wqb + (size_t)n0 * 768;
  const ushort* wkn = wkb + (size_t)n0 * 768;
  const ushort* wvn = wvb + (size_t)n0 * 768;

  const int rsub = lane >> 2;
  const int coff = (((lane & 3) ^ ((rsub >> 1) & 3)) << 3);
  const int wrow = wid * 16;

  auto stage = [&](int buf, int k0) {
#pragma unroll
    for (int rnd = 0; rnd < 2; ++rnd) {
      const int row0 = rnd * 64 + wrow;
      gload_lds16(&xm[(size_t)(row0 + rsub) * 768 + k0 + coff], &SM[buf][row0 * 32]);
    }
    gload_lds16(&wqn[(size_t)(wrow + rsub) * 768 + k0 + coff], &SM[buf][4096 + wrow * 32]);
    gload_lds16(&wkn[(size_t)(wrow + rsub) * 768 + k0 + coff], &SM[buf][6144 + wrow * 32]);
    gload_lds16(&wvn[(size_t)(wrow + rsub) * 768 + k0 + coff], &SM[buf][8192 + wrow * 32]);
  };

  f32x4 acc[3][2][4] = {};
  stage(0, 0);

  for (int kt = 0; kt < 24; ++kt) {
    const int cur = kt & 1;
    asm volatile("s_waitcnt vmcnt(0)" ::: "memory");
    __syncthreads();
    if (kt + 1 < 24) stage(cur ^ 1, (kt + 1) * 32);

    const ushort* bp = &SM[cur][0];
    bf16x8 a[2];
#pragma unroll
    for (int i = 0; i < 2; ++i) {
      const int row = wid * 32 + i * 16 + li;
      a[i] = *reinterpret_cast<const bf16x8*>(
          &bp[row * 32 + ((g ^ ((row >> 1) & 3)) << 3)]);
    }
#pragma unroll
    for (int o = 0; o < 3; ++o) {
      const int off = 4096 + o * 2048;
      bf16x8 b[4];
#pragma unroll
      for (int j = 0; j < 4; ++j) {
        const int row = j * 16 + li;
        b[j] = *reinterpret_cast<const bf16x8*>(
            &bp[off + row * 32 + ((g ^ ((row >> 1) & 3)) << 3)]);
      }
      __builtin_amdgcn_s_setprio(1);
#pragma unroll
      for (int i = 0; i < 2; ++i)
#pragma unroll
        for (int j = 0; j < 4; ++j)
          acc[o][i][j] = __builtin_amdgcn_mfma_f32_16x16x32_bf16(a[i], b[j], acc[o][i][j], 0, 0, 0);
      __builtin_amdgcn_s_setprio(0);
    }
  }

  ushort* Cs = &SM[0][0];
  const int b0 = m0 >> 11, sb = m0 & 2047;

  // ---- Q + K epilogue (two 128x64 tiles, swizzled LDS round-trip) ----
  __syncthreads();
#pragma unroll
  for (int o = 0; o < 2; ++o)
#pragma unroll
    for (int i = 0; i < 2; ++i)
#pragma unroll
      for (int j = 0; j < 4; ++j)
#pragma unroll
        for (int rr = 0; rr < 4; ++rr) {
          const int row = wid * 32 + i * 16 + g * 4 + rr;
          const int col = j * 16 + li;
          const int pc = ((((col >> 3) ^ (row & 7)) << 3) | (col & 7));
          const float v = acc[o][i][j][rr] * (o == 0 ? qscale : 1.0f);
          Cs[o * 8192 + row * 64 + pc] = f2bf(v);
        }
  __syncthreads();
  {
    const int row = tid >> 1, half = tid & 1;
    const int m = m0 + row;
    const size_t rb = (((size_t)b0 * H + slab) * S + (m & 2047)) * HD + half * 32;
    ushort* dq = &qb[rb];
    ushort* dk = &kb_[rb];
#pragma unroll
    for (int c8 = 0; c8 < 4; ++c8) {
      const int col = half * 32 + c8 * 8;
      const int chunk = (col >> 3) ^ (row & 7);
      *reinterpret_cast<bf16x8*>(&dq[c8 * 8]) =
          *reinterpret_cast<const bf16x8*>(&Cs[row * 64 + chunk * 8]);
      *reinterpret_cast<bf16x8*>(&dk[c8 * 8]) =
          *reinterpret_cast<const bf16x8*>(&Cs[8192 + row * 64 + chunk * 8]);
    }
  }

  // ---- V epilogue: write transposed Cs_v[64 feat][128 tok] ----
  __syncthreads();
#pragma unroll
  for (int i = 0; i < 2; ++i)
#pragma unroll
    for (int j = 0; j < 4; ++j)
#pragma unroll
      for (int rr = 0; rr < 4; ++rr) {
        const int tok = wid * 32 + i * 16 + g * 4 + rr;
        const int feat = j * 16 + li;
        const int pc = ((((tok >> 3) ^ (feat & 7)) << 3) | (tok & 7));
        Cs[feat * 128 + pc] = f2bf(acc[2][i][j][rr]);
      }
  __syncthreads();
  {
    const int feat = tid >> 2, qtr = tid & 3;
    ushort* dv = &vtb[(((size_t)b0 * H + slab) * HD + feat) * S + sb + qtr * 32];
#pragma unroll
    for (int c8 = 0; c8 < 4; ++c8) {
      const int tok = qtr * 32 + c8 * 8;
      const int chunk = (tok >> 3) ^ (feat & 7);
      *reinterpret_cast<bf16x8*>(&dv[c8 * 8]) =
          *reinterpret_cast<const bf16x8*>(&Cs[feat * 128 + chunk * 8]);
    }
  }
}

// ---------------- WO GEMM (round-10 best): 64x128 tiles, (128,6), 3-deep ----------------
__global__ __launch_bounds__(256) void gemm_wo(const ushort* __restrict__ A,
                                               const ushort* __restrict__ W,
                                               float* __restrict__ out_f,
                                               const float* __restrict__ bias) {
  __shared__ ushort SM[3][6144];
  const int tid = threadIdx.x;
  const int lane = tid & 63, wid = tid >> 6;
  const int g = lane >> 4, li = lane & 15;
  const int wm = wid >> 1, wn = wid & 1;
  const int m0 = blockIdx.x * 64, n0 = blockIdx.y * 128;

  const int rsub = lane >> 2;
  const int coff = (((lane & 3) ^ ((rsub >> 1) & 3)) << 3);

  auto stage = [&](int buf, int k0) {
    gload_lds16(&A[(size_t)(m0 + wid * 16 + rsub) * 768 + k0 + coff],
                &SM[buf][wid * 16 * 32]);
#pragma unroll
    for (int rnd = 0; rnd < 2; ++rnd) {
      const int row0 = rnd * 64 + wid * 16;
      gload_lds16(&W[(size_t)(n0 + row0 + rsub) * 768 + k0 + coff],
                  &SM[buf][2048 + row0 * 32]);
    }
  };

  f32x4 acc[2][4] = {};
  stage(0, 0);
  stage(1, 32);

  int cur = 0, pre = 2;
  for (int kt = 0; kt < 24; ++kt) {
    if (kt < 23) asm volatile("s_waitcnt vmcnt(3) lgkmcnt(0)" ::: "memory");
    else         asm volatile("s_waitcnt vmcnt(0) lgkmcnt(0)" ::: "memory");
    __builtin_amdgcn_s_barrier();
    if (kt + 2 < 24) stage(pre, (kt + 2) * 32);

    bf16x8 a[2], b[4];
#pragma unroll
    for (int i = 0; i < 2; ++i) {
      const int row = wm * 32 + i * 16 + li;
      a[i] = *reinterpret_cast<const bf16x8*>(
          &SM[cur][row * 32 + ((g ^ ((row >> 1) & 3)) << 3)]);
    }
#pragma unroll
    for (int j = 0; j < 4; ++j) {
      const int row = wn * 64 + j * 16 + li;
      b[j] = *reinterpret_cast<const bf16x8*>(
          &SM[cur][2048 + row * 32 + ((g ^ ((row >> 1) & 3)) << 3)]);
    }
    __builtin_amdgcn_s_setprio(1);
#pragma unroll
    for (int i = 0; i < 2; ++i)
#pragma unroll
      for (int j = 0; j < 4; ++j)
        acc[i][j] = __builtin_amdgcn_mfma_f32_16x16x32_bf16(a[i], b[j], acc[i][j], 0, 0, 0);
    __builtin_amdgcn_s_setprio(0);

    cur = (cur == 2) ? 0 : cur + 1;
    pre = (pre == 2) ? 0 : pre + 1;
  }

#pragma unroll
  for (int i = 0; i < 2; ++i)
#pragma unroll
    for (int j = 0; j < 4; ++j)
#pragma unroll
      for (int r = 0; r < 4; ++r) {
        const int m = m0 + wm * 32 + i * 16 + g * 4 + r;
        const int n = n0 + wn * 64 + j * 16 + li;
        out_f[(size_t)m * 768 + n] = acc[i][j][r] + bias[n];
      }
}

// ---------------- flash attention: 512-thread blocks, 2 causal pairs share KV ----------------
// Fix vs round-19: total static LDS = 51,200 B (<= 64 KB launch cap). Ps halved to
// [8][16][72] by processing the two fragments SEQUENTIALLY through the per-wave
// buffer (safe: per-wave DS ops are in-order; buffer is wave-private).
// Block k2 (8 per head) covers pairs (2k2, 31-2k2) and (2k2+1, 30-2k2-1);
// waves 0-3 own pair A, waves 4-7 pair B; all 8 waves consume each staged tile
// -> staging per lane = 1 K-load + 1 VT-load. l via MFMA-with-ones.
__global__ __launch_bounds__(512) void attn_kernel(const ushort* __restrict__ Q,
                                                   const ushort* __restrict__ K,
                                                   const ushort* __restrict__ VT,
                                                   ushort* __restrict__ ctx) {
  __shared__ ushort Ks[2][64 * 64];    // 16 KB
  __shared__ ushort Vts[2][64 * 64];   // 16 KB
  __shared__ ushort Ps[8][16][72];     // 18.4 KB -> total 51,200 B

  const int tid = threadIdx.x;
  const int lane = tid & 63, wid = tid >> 6;   // wid 0..7
  const int g = lane >> 4, li = lane & 15;

  const int wg = blockIdx.x;
  const int xcd = wg & 7;
  const int rest = wg >> 3;          // 0..47, k2 ascending -> longest first
  const int headi = rest % 6;
  const int k2 = rest / 6;           // 0..7
  const int bh = headi * 8 + xcd;

  const int pA = 2 * k2;
  const int myp = pA + (wid >> 2);   // this wave's pair index (0..15)
  const int qL = 64 * (31 - myp), qS = 64 * myp;
  const int wr = (wid & 3) * 16;     // wave's 16-row slice within each tile
  const int myNkt = 32 - myp;
  const int nkt = 32 - pA;           // block trip count

  const size_t base = (size_t)bh * S * HD;
  const size_t vtbase = (size_t)bh * HD * S;

  bf16x8 aq[2][2];
#pragma unroll
  for (int f = 0; f < 2; ++f) {
    const size_t qr = base + (size_t)((f ? qS : qL) + wr + li) * HD;
#pragma unroll
    for (int c = 0; c < 2; ++c)
      aq[f][c] = *reinterpret_cast<const bf16x8*>(&Q[qr + c * 32 + g * 8]);
  }

  f32x4 acc[2][4] = {};
  f32x4 accl[2] = {};
  const uint one2 = 0x3F803F80u;
  uint4 ouv = {one2, one2, one2, one2};
  const bf16x8 ones8 = *reinterpret_cast<const bf16x8*>(&ouv);

  // staging: wave wid covers rows wid*8..+7 of each 64-row tile
  const int rsub = lane >> 3;
  const int srow = wid * 8 + rsub;
  const int c8e = (((lane & 7) ^ rsub) << 3);

  auto stage = [&](int buf, int k0) {
    gload_lds16(&K[base + (size_t)(k0 + srow) * HD + c8e], &Ks[buf][(wid * 8) << 6]);
    gload_lds16(&VT[vtbase + (size_t)srow * S + k0 + c8e], &Vts[buf][(wid * 8) << 6]);
  };

  stage(0, 0);

  for (int kt = 0; kt < nkt; ++kt) {
    const int cur = kt & 1;
    const int k0 = kt * 64;

    asm volatile("s_waitcnt vmcnt(0)" ::: "memory");
    __syncthreads();
    if (kt + 1 < nkt) stage(cur ^ 1, k0 + 64);

    if (kt < myNkt) {
      const bool doS = (kt <= myp);

      // ---- QK^T swapped (both fragments) ----
      f32x4 sc[2][4];
      __builtin_amdgcn_s_setprio(1);
#pragma unroll
      for (int ct = 0; ct < 4; ++ct) {
        const int row = ct * 16 + li, r7 = row & 7;
        const ushort* kr = &Ks[cur][row << 6];
        bf16x8 kb0 = *reinterpret_cast<const bf16x8*>(&kr[(g ^ r7) << 3]);
        bf16x8 kb1 = *reinterpret_cast<const bf16x8*>(&kr[((4 + g) ^ r7) << 3]);
        {
          f32x4 z = {};
          z = __builtin_amdgcn_mfma_f32_16x16x32_bf16(kb0, aq[0][0], z, 0, 0, 0);
          z = __builtin_amdgcn_mfma_f32_16x16x32_bf16(kb1, aq[0][1], z, 0, 0, 0);
          sc[0][ct] = z;
        }
        if (doS) {
          f32x4 z = {};
          z = __builtin_amdgcn_mfma_f32_16x16x32_bf16(kb0, aq[1][0], z, 0, 0, 0);
          z = __builtin_amdgcn_mfma_f32_16x16x32_bf16(kb1, aq[1][1], z, 0, 0, 0);
          sc[1][ct] = z;
        }
      }
      __builtin_amdgcn_s_setprio(0);

      if (kt == myNkt - 1) {  // f=0 diagonal
        const int q = qL + wr + li;
#pragma unroll
        for (int ct = 0; ct < 4; ++ct)
#pragma unroll
          for (int r = 0; r < 4; ++r)
            if (k0 + ct * 16 + 4 * g + r > q) sc[0][ct][r] = -1e30f;
      }
      if (kt == myp) {  // f=1 diagonal
        const int q = qS + wr + li;
#pragma unroll
        for (int ct = 0; ct < 4; ++ct)
#pragma unroll
          for (int r = 0; r < 4; ++r)
            if (k0 + ct * 16 + 4 * g + r > q) sc[1][ct][r] = -1e30f;
      }

      // ---- sequential fragments through the halved per-wave P buffer ----
#pragma unroll
      for (int f = 0; f < 2; ++f) {
        if (f == 1 && !doS) break;
#pragma unroll
        for (int ct = 0; ct < 4; ++ct) {
          float p0 = __builtin_amdgcn_exp2f(sc[f][ct][0]);
          float p1 = __builtin_amdgcn_exp2f(sc[f][ct][1]);
          float p2 = __builtin_amdgcn_exp2f(sc[f][ct][2]);
          float p3 = __builtin_amdgcn_exp2f(sc[f][ct][3]);
          uint2 pw;
          pw.x = cvt_pk_bf16(p0, p1);
          pw.y = cvt_pk_bf16(p2, p3);
          *reinterpret_cast<uint2*>(&Ps[wid][li][ct * 16 + 4 * g]) = pw;
        }
        bf16x8 pa0 = *reinterpret_cast<const bf16x8*>(&Ps[wid][li][g * 8]);
        bf16x8 pa1 = *reinterpret_cast<const bf16x8*>(&Ps[wid][li][32 + g * 8]);
        __builtin_amdgcn_s_setprio(1);
        accl[f] = __builtin_amdgcn_mfma_f32_16x16x32_bf16(pa0, ones8, accl[f], 0, 0, 0);
        accl[f] = __builtin_amdgcn_mfma_f32_16x16x32_bf16(pa1, ones8, accl[f], 0, 0, 0);
#pragma unroll
        for (int dt = 0; dt < 4; ++dt) {
          const int row = dt * 16 + li, r7 = row & 7;
          const ushort* vr = &Vts[cur][row << 6];
          bf16x8 vb0 = *reinterpret_cast<const bf16x8*>(&vr[(g ^ r7) << 3]);
          bf16x8 vb1 = *reinterpret_cast<const bf16x8*>(&vr[((4 + g) ^ r7) << 3]);
          acc[f][dt] = __builtin_amdgcn_mfma_f32_16x16x32_bf16(pa0, vb0, acc[f][dt], 0, 0, 0);
          acc[f][dt] = __builtin_amdgcn_mfma_f32_16x16x32_bf16(pa1, vb1, acc[f][dt], 0, 0, 0);
        }
        __builtin_amdgcn_s_setprio(0);
      }
    }
  }

  // ---- normalize + store: accl[f][r] IS l for this lane's row ----
  const int b = bh / H, h = bh % H;
#pragma unroll
  for (int f = 0; f < 2; ++f) {
#pragma unroll
    for (int r = 0; r < 4; ++r) {
      const float inv = 1.0f / accl[f][r];
      const int s = (f ? qS : qL) + wr + 4 * g + r;
#pragma unroll
      for (int dt = 0; dt < 4; ++dt)
        ctx[((size_t)(b * S + s)) * D + h * HD + dt * 16 + li] =
            f2bf(acc[f][dt][r] * inv);
    }
  }
}

extern "C" void kernel_launch(void* const* d_in, const int* in_sizes, int n_in,
                              void* d_out, int out_size, void* d_ws, size_t ws_size,
                              hipStream_t stream) {
  (void)in_sizes; (void)n_in; (void)out_size; (void)ws_size;
  const float* x  = (const float*)d_in[0];
  const float* wq = (const float*)d_in[1];
  const float* wk = (const float*)d_in[2];
  const float* wv = (const float*)d_in[3];
  const float* wo = (const float*)d_in[4];
  const float* bo = (const float*)d_in[5];
  float* out = (float*)d_out;

  const size_t xn = (size_t)M_TOT * D;
  const size_t wn = (size_t)D * D;

  ushort* p = (ushort*)d_ws;
  ushort* x_bf  = p; p += xn;
  ushort* wq_bf = p; p += wn;
  ushort* wk_bf = p; p += wn;
  ushort* wv_bf = p; p += wn;
  ushort* wo_bf = p; p += wn;
  ushort* q_bf  = p; p += xn;
  ushort* k_bf  = p; p += xn;
  ushort* vt_bf = p; p += xn;
  ushort* ctx_bf = x_bf;  // alias: x_bf dead after QKV GEMM

  cast_all<<<8448, 256, 0, stream>>>(x, wq, wk, wv, wo,
                                     x_bf, wq_bf, wk_bf, wv_bf, wo_bf);

  const float QSCALE = 0.125f * 1.44269504f;  // 1/sqrt(64) * log2(e) folded into Q
  gemm_qkv<<<768, 256, 0, stream>>>(x_bf, wq_bf, wk_bf, wv_bf,
                                    q_bf, k_bf, vt_bf, QSCALE);

  attn_kernel<<<384, 512, 0, stream>>>(q_bf, k_bf, vt_bf, ctx_bf);

  gemm_wo<<<dim3(128, 6), 256, 0, stream>>>(ctx_bf, wo_bf, out, bo);
}